// Round 11
// baseline (199.972 us; speedup 1.0000x reference)
//
#include <hip/hip_runtime.h>

#define N_NODES 100000
#define N_EDGES 3200000
#define N_FEAT  512
#define HID     16
#define N_CLASS 40

#define BSHIFT  9                      // 512 nodes per bucket
#define BMASK   ((1 << BSHIFT) - 1)
#define NB      196                    // ceil(100000 / 512)
#define CAP     18432                  // padded bucket region (mean 16384, +16 sigma)
#define EPB     4096                   // edges per binning block

#define BIN_BLOCKS  ((N_EDGES + EPB - 1) / EPB)   // 782
#define NT          (N_NODES / 16)                // 6250 lin1 tiles
#define LIN1_BLOCKS ((NT + 3) / 4)                // 1563

typedef __attribute__((ext_vector_type(8))) short bf16x8;
typedef __attribute__((ext_vector_type(4))) float f32x4;

__device__ inline short2 split_bf(float v) {
    const unsigned u = __float_as_uint(v);
    const short hi = (short)(u >> 16);
    const float hf = __uint_as_float(u & 0xFFFF0000u);
    const short lo = (short)(__float_as_uint(v - hf) >> 16);
    return make_short2(hi, lo);
}
__device__ inline unsigned short f2bf_rtn(float v) {
    unsigned u = __float_as_uint(v);
    u += 0x7FFFu + ((u >> 16) & 1u);
    return (unsigned short)(u >> 16);
}
__device__ inline float bf2f(unsigned short u) {
    return __uint_as_float(((unsigned)u) << 16);
}

// ================= Fused: CSR binning (blocks 0..781) + lin1 (rest) =========
struct BinSmem {
    int hist[NB]; int lofs[NB]; int base[NB]; int rk[NB];
    int buf[256]; int stage[EPB]; unsigned short sbkt[EPB];
};
struct Lin1Smem { short bfH[16 * 64 * 8]; short bfL[16 * 64 * 8]; };

__device__ void bin_body(char* smemraw,
                         const int* __restrict__ src,
                         const int* __restrict__ dst,
                         int* __restrict__ cursor,
                         int* __restrict__ binned) {
    BinSmem& sm = *(BinSmem*)smemraw;
    const int t = threadIdx.x;
    for (int i = t; i < NB; i += 256) { sm.hist[i] = 0; sm.rk[i] = 0; }
    __syncthreads();

    const int e0 = blockIdx.x * EPB;
    int bk[EPB / 256];
    int vv[EPB / 256];
#pragma unroll
    for (int k = 0; k < EPB / 256; k++) {
        const int e = e0 + k * 256 + t;
        if (e < N_EDGES) {
            const int d = dst[e], s = src[e];
            bk[k] = d >> BSHIFT;
            vv[k] = (s << BSHIFT) | (d & BMASK);
            atomicAdd(&sm.hist[bk[k]], 1);
        } else bk[k] = -1;
    }
    __syncthreads();

    {
        const int v = (t < NB) ? sm.hist[t] : 0;
        sm.buf[t] = v; __syncthreads();
        for (int o = 1; o < 256; o <<= 1) {
            const int a = (t >= o) ? sm.buf[t - o] : 0;
            __syncthreads();
            sm.buf[t] += a;
            __syncthreads();
        }
        if (t < NB) sm.lofs[t] = sm.buf[t] - v;
    }
    if (t < NB && sm.hist[t] > 0)
        sm.base[t] = t * CAP + atomicAdd(&cursor[t], sm.hist[t]);

#pragma unroll
    for (int k = 0; k < EPB / 256; k++) {
        if (bk[k] >= 0) {
            const int r = atomicAdd(&sm.rk[bk[k]], 1);
            const int slot = sm.lofs[bk[k]] + r;
            sm.stage[slot] = vv[k];
            sm.sbkt[slot] = (unsigned short)bk[k];
        }
    }
    __syncthreads();

    const int nloc = min(EPB, N_EDGES - e0);
    for (int s2 = t; s2 < nloc; s2 += 256) {
        const int b = sm.sbkt[s2];
        binned[sm.base[b] + (s2 - sm.lofs[b])] = sm.stage[s2];
    }
}

__device__ void lin1_body(char* smemraw, int lblk,
                          const float* __restrict__ x,
                          const float* __restrict__ w1,
                          const float* __restrict__ b1,
                          unsigned short* __restrict__ xnb,
                          float* __restrict__ normv) {
    Lin1Smem& sm = *(Lin1Smem*)smemraw;
    const int t = threadIdx.x;
    for (int f = t; f < 16 * 64; f += 256) {
        const int kt  = f >> 6;
        const int ln  = f & 63;
        const int col = ln & 15;
        const int k0  = kt * 32 + (ln >> 4) * 8;
        const float4 v0 = *(const float4*)(w1 + col * N_FEAT + k0);
        const float4 v1 = *(const float4*)(w1 + col * N_FEAT + k0 + 4);
        bf16x8 hh, ll;
        short2 r;
        r = split_bf(v0.x); hh[0] = r.x; ll[0] = r.y;
        r = split_bf(v0.y); hh[1] = r.x; ll[1] = r.y;
        r = split_bf(v0.z); hh[2] = r.x; ll[2] = r.y;
        r = split_bf(v0.w); hh[3] = r.x; ll[3] = r.y;
        r = split_bf(v1.x); hh[4] = r.x; ll[4] = r.y;
        r = split_bf(v1.y); hh[5] = r.x; ll[5] = r.y;
        r = split_bf(v1.z); hh[6] = r.x; ll[6] = r.y;
        r = split_bf(v1.w); hh[7] = r.x; ll[7] = r.y;
        ((bf16x8*)sm.bfH)[f] = hh;
        ((bf16x8*)sm.bfL)[f] = ll;
    }
    __syncthreads();

    const int wv   = t >> 6;
    const int l    = t & 63;
    const int tile = lblk * 4 + wv;
    if (tile >= NT) return;

    const int r0 = tile * 16;
    const float* xp = x + (size_t)(r0 + (l & 15)) * N_FEAT + ((l >> 4) * 8);

    f32x4 acc = {0.f, 0.f, 0.f, 0.f};
    float4 c0 = *(const float4*)(xp);
    float4 c1 = *(const float4*)(xp + 4);
#pragma unroll
    for (int kt = 0; kt < 16; ++kt) {
        float4 n0, n1;
        if (kt < 15) {
            n0 = *(const float4*)(xp + (kt + 1) * 32);
            n1 = *(const float4*)(xp + (kt + 1) * 32 + 4);
        }
        bf16x8 ah, al;
        short2 r;
        r = split_bf(c0.x); ah[0] = r.x; al[0] = r.y;
        r = split_bf(c0.y); ah[1] = r.x; al[1] = r.y;
        r = split_bf(c0.z); ah[2] = r.x; al[2] = r.y;
        r = split_bf(c0.w); ah[3] = r.x; al[3] = r.y;
        r = split_bf(c1.x); ah[4] = r.x; al[4] = r.y;
        r = split_bf(c1.y); ah[5] = r.x; al[5] = r.y;
        r = split_bf(c1.z); ah[6] = r.x; al[6] = r.y;
        r = split_bf(c1.w); ah[7] = r.x; al[7] = r.y;
        const bf16x8 bh = ((const bf16x8*)sm.bfH)[kt * 64 + l];
        const bf16x8 bl = ((const bf16x8*)sm.bfL)[kt * 64 + l];
        acc = __builtin_amdgcn_mfma_f32_16x16x32_bf16(ah, bh, acc, 0, 0, 0);
        acc = __builtin_amdgcn_mfma_f32_16x16x32_bf16(al, bh, acc, 0, 0, 0);
        acc = __builtin_amdgcn_mfma_f32_16x16x32_bf16(ah, bl, acc, 0, 0, 0);
        c0 = n0; c1 = n1;
    }

    const float bias = b1[l & 15];
#pragma unroll
    for (int r = 0; r < 4; ++r) {
        const float v = fmaxf(acc[r] + bias, 0.f);
        float ss = v * v;
        ss += __shfl_xor(ss, 1); ss += __shfl_xor(ss, 2);
        ss += __shfl_xor(ss, 4); ss += __shfl_xor(ss, 8);
        const float nrm = sqrtf(ss);
        const float rn  = 1.f / fmaxf(nrm, 1e-12f);
        const int row = r0 + (l >> 4) * 4 + r;
        xnb[(size_t)row * HID + (l & 15)] = f2bf_rtn(v * rn);
        if ((l & 15) == 0) normv[row] = nrm;
    }
}

__global__ __launch_bounds__(256) void k_bin_lin1(const int* __restrict__ src,
                                                  const int* __restrict__ dst,
                                                  int* __restrict__ cursor,
                                                  int* __restrict__ binned,
                                                  const float* __restrict__ x,
                                                  const float* __restrict__ w1,
                                                  const float* __restrict__ b1,
                                                  unsigned short* __restrict__ xnb,
                                                  float* __restrict__ normv) {
    __shared__ __align__(16) char smem[sizeof(Lin1Smem) > sizeof(BinSmem)
                                       ? sizeof(Lin1Smem) : sizeof(BinSmem)];
    if (blockIdx.x < BIN_BLOCKS)
        bin_body(smem, src, dst, cursor, binned);
    else
        lin1_body(smem, blockIdx.x - BIN_BLOCKS, x, w1, b1, xnb, normv);
}

// ============================== k_csr =======================================
__global__ __launch_bounds__(512) void k_csr(const int* __restrict__ cursor,
                                             int* __restrict__ binned,
                                             int* __restrict__ row_start,
                                             unsigned short* __restrict__ row_cnt) {
    __shared__ int cnts[512];
    __shared__ int cur[512];
    __shared__ int buf[512];
    __shared__ int lcsr[CAP];

    const int t = threadIdx.x;
    const int b = blockIdx.x;
    const int s0 = b * CAP;
    const int n = cursor[b];

    cnts[t] = 0;
    __syncthreads();
    for (int i = t; i < n; i += 512)
        atomicAdd(&cnts[binned[s0 + i] & BMASK], 1);
    __syncthreads();

    {
        const int v = cnts[t];
        buf[t] = v; __syncthreads();
        for (int o = 1; o < 512; o <<= 1) {
            const int a = (t >= o) ? buf[t - o] : 0;
            __syncthreads();
            buf[t] += a;
            __syncthreads();
        }
        cur[t] = buf[t] - v;
        const int node = (b << BSHIFT) + t;
        if (node < N_NODES) {
            row_start[node] = s0 + cur[t];
            row_cnt[node]   = (unsigned short)v;
        }
    }
    __syncthreads();

    for (int i = t; i < n; i += 512) {
        const int v = binned[s0 + i];
        const int p = atomicAdd(&cur[v & BMASK], 1);
        lcsr[p] = v >> BSHIFT;
    }
    __syncthreads();

    for (int i = t; i < n; i += 512) binned[s0 + i] = lcsr[i];
}

// ============================== Fused AGNN gather ===========================
// 16 lanes per dst node. Lane g loads src row g ONCE (32 B) — used for both
// the cosine logit AND per-lane feature accumulation acc[f] += w*norm*row[f]
// (no col re-loads, no per-batch shuffles). One 15-shfl butterfly per NODE
// (HW-verified in r6) deposits feature l on lane l. LAST=1: fuse
// lin2 + log_softmax into the epilogue (W2 staged in LDS, padded [40][17]).
template <int LAST>
__global__ __launch_bounds__(256) void k_agnn(const int* __restrict__ row_start,
                                              const unsigned short* __restrict__ row_cnt,
                                              const int* __restrict__ csr_src,
                                              const unsigned short* __restrict__ xnb,
                                              const float* __restrict__ normv,
                                              const float* __restrict__ betap,
                                              const float* __restrict__ w2,
                                              const float* __restrict__ b2,
                                              float* __restrict__ out,
                                              unsigned short* __restrict__ outb,
                                              float* __restrict__ out_norm) {
    __shared__ float w2s[N_CLASS][HID + 1];
    __shared__ float b2s[N_CLASS];
    if (LAST) {
        for (int i = threadIdx.x; i < N_CLASS * HID; i += 256)
            w2s[i / HID][i % HID] = w2[i];
        if (threadIdx.x < N_CLASS) b2s[threadIdx.x] = b2[threadIdx.x];
        __syncthreads();
    }

    const int l16  = threadIdx.x & 15;
    const int node = (blockIdx.x * 256 + threadIdx.x) >> 4;   // grid exact
    const float beta  = betap ? betap[0] : 1.0f;
    const float shift = fabsf(beta);

    const int rs  = row_start[node];
    const int cnt = row_cnt[node];

    // dst row -> 16 f32 regs
    const bf16x8* xd = (const bf16x8*)(xnb + (size_t)node * HID);
    const bf16x8 dlo = xd[0], dhi = xd[1];
    float dd[16];
#pragma unroll
    for (int i = 0; i < 8; i++) {
        dd[i]     = bf2f((unsigned short)dlo[i]);
        dd[i + 8] = bf2f((unsigned short)dhi[i]);
    }

    float acc[16];
#pragma unroll
    for (int i = 0; i < 16; i++) acc[i] = 0.f;
    float swl = 0.f;

    // prologue: prefetch batch 0
    bool ok = (l16 < cnt);
    int sidx = ok ? csr_src[rs + l16] : 0;
    const bf16x8* xs0 = (const bf16x8*)(xnb + (size_t)sidx * HID);
    bf16x8 slo = xs0[0], shi = xs0[1];
    float nj = normv[sidx];

    for (int t = 0; t < cnt; t += 16) {
        // prefetch batch t+16
        const int k2 = t + 16 + l16;
        const bool ok2 = (k2 < cnt);
        const int sidx2 = ok2 ? csr_src[rs + k2] : 0;
        const bf16x8* xs2 = (const bf16x8*)(xnb + (size_t)sidx2 * HID);
        const bf16x8 slo2 = xs2[0], shi2 = xs2[1];
        const float nj2 = normv[sidx2];

        // convert row once; use for dot AND aggregation
        float sr[16];
#pragma unroll
        for (int i = 0; i < 8; i++) {
            sr[i]     = bf2f((unsigned short)slo[i]);
            sr[i + 8] = bf2f((unsigned short)shi[i]);
        }
        float p0 = 0.f, p1 = 0.f, p2 = 0.f, p3 = 0.f;
#pragma unroll
        for (int i = 0; i < 4; i++) {
            p0 += sr[i]      * dd[i];
            p1 += sr[i + 4]  * dd[i + 4];
            p2 += sr[i + 8]  * dd[i + 8];
            p3 += sr[i + 12] * dd[i + 12];
        }
        const float dot = (p0 + p1) + (p2 + p3);
        const float w = ok ? __expf(beta * dot - shift) : 0.f;
        swl += w;
        const float wn = w * nj;
#pragma unroll
        for (int i = 0; i < 16; i++) acc[i] += wn * sr[i];

        sidx = sidx2; slo = slo2; shi = shi2; nj = nj2; ok = ok2;
    }

    // transpose-reduce: lane l16 ends with Sum over lanes of acc[.][l16]
#pragma unroll
    for (int m = 1; m < 16; m <<= 1) {
#pragma unroll
        for (int r = 0; r < 16; r += 2 * m) {
            const float sel  = (l16 & m) ? acc[r] : acc[r + m];
            const float got  = __shfl_xor(sel, m);
            const float mine = (l16 & m) ? acc[r + m] : acc[r];
            acc[r] = mine + got;
        }
    }
    float sw = swl;
    sw += __shfl_xor(sw, 1); sw += __shfl_xor(sw, 2);
    sw += __shfl_xor(sw, 4); sw += __shfl_xor(sw, 8);

    const float v = acc[0] / fmaxf(sw, 1e-16f);

    if (!LAST) {
        float ss = v * v;
        ss += __shfl_xor(ss, 1); ss += __shfl_xor(ss, 2);
        ss += __shfl_xor(ss, 4); ss += __shfl_xor(ss, 8);
        const float nrm = sqrtf(ss);
        const float rn  = 1.f / fmaxf(nrm, 1e-12f);
        outb[(size_t)node * HID + l16] = f2bf_rtn(v * rn);
        if (l16 == 0) out_norm[node] = nrm;
    } else {
        // fused lin2 + log_softmax
        float vv[16];
#pragma unroll
        for (int k = 0; k < 16; k++) vv[k] = __shfl(v, k, 16);
        const int c0 = l16, c1 = l16 + 16, c2 = l16 + 32;   // c2 valid if l16<8
        float lg0 = b2s[c0], lg1 = b2s[c1];
        float lg2 = (l16 < 8) ? b2s[c2] : -3.0e38f;
#pragma unroll
        for (int k = 0; k < 16; k++) {
            lg0 += vv[k] * w2s[c0][k];
            lg1 += vv[k] * w2s[c1][k];
            if (l16 < 8) lg2 += vv[k] * w2s[c2][k];
        }
        float m = fmaxf(lg0, lg1);
        if (l16 < 8) m = fmaxf(m, lg2);
        m = fmaxf(m, __shfl_xor(m, 1)); m = fmaxf(m, __shfl_xor(m, 2));
        m = fmaxf(m, __shfl_xor(m, 4)); m = fmaxf(m, __shfl_xor(m, 8));
        float s = __expf(lg0 - m) + __expf(lg1 - m)
                + ((l16 < 8) ? __expf(lg2 - m) : 0.f);
        s += __shfl_xor(s, 1); s += __shfl_xor(s, 2);
        s += __shfl_xor(s, 4); s += __shfl_xor(s, 8);
        const float lse = m + __logf(s);

        float* orow = out + (size_t)node * N_CLASS;
        orow[c0] = lg0 - lse;
        orow[c1] = lg1 - lse;
        if (l16 < 8) orow[c2] = lg2 - lse;
    }
}

// ============================== Launch ======================================
extern "C" void kernel_launch(void* const* d_in, const int* in_sizes, int n_in,
                              void* d_out, int out_size, void* d_ws, size_t ws_size,
                              hipStream_t stream) {
    const float* x     = (const float*)d_in[0];
    const int*   ei    = (const int*)  d_in[1];   // [2][E]: row0=src, row1=dst
    const float* w1    = (const float*)d_in[2];
    const float* b1    = (const float*)d_in[3];
    const float* beta2 = (const float*)d_in[4];
    const float* w2    = (const float*)d_in[5];
    const float* b2    = (const float*)d_in[6];
    float* out = (float*)d_out;

    const int* srcp = ei;
    const int* dstp = ei + N_EDGES;

    // workspace layout (~22 MB)
    unsigned short* xnb1 = (unsigned short*)d_ws;        // [N,16] bf16 unit rows
    unsigned short* xnb2 = xnb1 + (size_t)N_NODES * HID; // [N,16] bf16
    float* norm1 = (float*)(xnb2 + (size_t)N_NODES * HID); // [N]
    float* norm2 = norm1 + N_NODES;                      // [N]
    int* row_start = (int*)(norm2 + N_NODES);            // [N]
    unsigned short* row_cnt = (unsigned short*)(row_start + N_NODES); // [N]
    int* cursor = (int*)(row_cnt + N_NODES + (N_NODES & 1)); // [NB]
    int* binned = cursor + NB + 2;                       // [NB*CAP] padded

    const int agnnGrid = N_NODES * HID / 256;          // 6250

    hipMemsetAsync(cursor, 0, NB * sizeof(int), stream);

    // ---- fused CSR-binning + lin1 (independent pipelines, one dispatch) ----
    k_bin_lin1<<<BIN_BLOCKS + LIN1_BLOCKS, 256, 0, stream>>>(
        srcp, dstp, cursor, binned, x, w1, b1, xnb1, norm1);

    k_csr<<<NB, 512, 0, stream>>>(cursor, binned, row_start, row_cnt);

    // ---- AGNN layers; layer2 fuses lin2 + log_softmax ----
    k_agnn<0><<<agnnGrid, 256, 0, stream>>>(row_start, row_cnt, binned, xnb1,
                                            norm1, nullptr, nullptr, nullptr,
                                            nullptr, xnb2, norm2);
    k_agnn<1><<<agnnGrid, 256, 0, stream>>>(row_start, row_cnt, binned, xnb2,
                                            norm2, beta2, w2, b2,
                                            out, nullptr, nullptr);
}